// Round 1
// baseline (746.753 us; speedup 1.0000x reference)
//
#include <hip/hip_runtime.h>
#include <hip/hip_bf16.h>

// out[s,d,b,k] = log( sum_n exp(x[s,d,b,n]) * acc[s,d,n,k] ) - log( sum_n acc[s,d,n,k] )
// S=32 D=8 B=256 N=512 K=512 ; SD = 256 independent 256x512x512 GEMMs.
// Fast path: split-bf16 (hi/lo) MFMA GEMM, both operands K-major (acc transposed in prep).

typedef __attribute__((ext_vector_type(8))) __bf16 bf16x8;
typedef __attribute__((ext_vector_type(4))) float f32x4;

#define SD_TOT 256
#define MB 256     // b per sd
#define NN 512     // n (contraction)
#define KK 512     // k (output cols)

__device__ inline unsigned short bf16rn(float f) {
  unsigned int u = __float_as_uint(f);
  u += 0x7fffu + ((u >> 16) & 1u);
  return (unsigned short)(u >> 16);
}
__device__ inline float bf16tof(unsigned short h) {
  return __uint_as_float(((unsigned int)h) << 16);
}

typedef __attribute__((address_space(1))) const unsigned char gas_byte;
typedef __attribute__((address_space(3))) unsigned char las_byte;
#define GLL16(gp, lp) __builtin_amdgcn_global_load_lds((gas_byte*)(const void*)(gp), (las_byte*)(void*)(lp), 16, 0, 0)

// ---------------- prep_x: E = exp(x), split to hi/lo bf16 planes -------------
__global__ __launch_bounds__(256) void prep_x(const float* __restrict__ x,
                                              unsigned short* __restrict__ Ehi,
                                              unsigned short* __restrict__ Elo) {
  size_t i = ((size_t)blockIdx.x * 256 + threadIdx.x) * 8;
  float4 v0 = *(const float4*)(x + i);
  float4 v1 = *(const float4*)(x + i + 4);
  float e[8] = {__expf(v0.x), __expf(v0.y), __expf(v0.z), __expf(v0.w),
                __expf(v1.x), __expf(v1.y), __expf(v1.z), __expf(v1.w)};
  unsigned short h[8], l[8];
#pragma unroll
  for (int j = 0; j < 8; ++j) {
    h[j] = bf16rn(e[j]);
    l[j] = bf16rn(e[j] - bf16tof(h[j]));
  }
  *(ushort4*)(Ehi + i)     = make_ushort4(h[0], h[1], h[2], h[3]);
  *(ushort4*)(Ehi + i + 4) = make_ushort4(h[4], h[5], h[6], h[7]);
  *(ushort4*)(Elo + i)     = make_ushort4(l[0], l[1], l[2], l[3]);
  *(ushort4*)(Elo + i + 4) = make_ushort4(l[4], l[5], l[6], l[7]);
}

// -------- prep_acc: transpose acc[sd][n][k] -> Bt[sd][k][n] split hi/lo, plus
//          logsum[sd][k] = log(sum_n acc).  One block = (sd, 64-wide k tile). --
__global__ __launch_bounds__(256) void prep_acc(const float* __restrict__ wacc,
                                                unsigned short* __restrict__ Bthi,
                                                unsigned short* __restrict__ Btlo,
                                                float* __restrict__ logsum) {
  __shared__ unsigned int tile[64 * 65];
  __shared__ float psum[4][64];
  const int t = threadIdx.x;
  const int sd = blockIdx.x >> 3;
  const int k0 = (blockIdx.x & 7) << 6;
  const int j = t & 63;       // k within tile (read phase)
  const int nq = t >> 6;      // 0..3
  const float* src = wacc + (size_t)sd * NN * KK + k0;
  float sum = 0.f;

  for (int c = 0; c < 8; ++c) {
    const int n0 = c * 64;
#pragma unroll
    for (int ii = 0; ii < 16; ++ii) {
      int nr = nq + 4 * ii;  // row in chunk
      float a = src[(size_t)(n0 + nr) * KK + j];
      sum += a;
      unsigned int h = bf16rn(a);
      unsigned int l = bf16rn(a - bf16tof((unsigned short)h));
      tile[nr * 65 + j] = h | (l << 16);
    }
    __syncthreads();
#pragma unroll
    for (int pp = 0; pp < 4; ++pp) {
      int kcol = (t >> 4) + 16 * pp;   // 0..63
      int nb = (t & 15) * 4;
      unsigned int w0 = tile[(nb + 0) * 65 + kcol];
      unsigned int w1 = tile[(nb + 1) * 65 + kcol];
      unsigned int w2 = tile[(nb + 2) * 65 + kcol];
      unsigned int w3 = tile[(nb + 3) * 65 + kcol];
      size_t ob = ((size_t)(sd * KK + k0 + kcol)) * NN + n0 + nb;
      *(ushort4*)(Bthi + ob) = make_ushort4((unsigned short)(w0 & 0xffffu), (unsigned short)(w1 & 0xffffu),
                                            (unsigned short)(w2 & 0xffffu), (unsigned short)(w3 & 0xffffu));
      *(ushort4*)(Btlo + ob) = make_ushort4((unsigned short)(w0 >> 16), (unsigned short)(w1 >> 16),
                                            (unsigned short)(w2 >> 16), (unsigned short)(w3 >> 16));
    }
    __syncthreads();
  }
  psum[nq][j] = sum;
  __syncthreads();
  if (t < 64) {
    float s = psum[0][t] + psum[1][t] + psum[2][t] + psum[3][t];
    logsum[sd * KK + k0 + t] = __logf(s);
  }
}

// ---------------- gemm: C = Ehi/lo * Bthi/lo^T (3-MFMA split), fused epilogue -
__global__ __launch_bounds__(256) void gemm_split(const unsigned short* __restrict__ Ehi,
                                                  const unsigned short* __restrict__ Elo,
                                                  const unsigned short* __restrict__ Bthi,
                                                  const unsigned short* __restrict__ Btlo,
                                                  const float* __restrict__ logsum,
                                                  float* __restrict__ out) {
  __shared__ __align__(16) unsigned short sAhi[128 * 64];
  __shared__ __align__(16) unsigned short sAlo[128 * 64];
  __shared__ __align__(16) unsigned short sBhi[128 * 64];
  __shared__ __align__(16) unsigned short sBlo[128 * 64];

  const int bx = blockIdx.x;
  // XCD-aware swizzle: 2048 blocks, 8 XCDs -> 256 consecutive logical tiles per XCD.
  const int wg = (bx & 7) * 256 + (bx >> 3);
  const int sd = wg >> 3;
  const int mt = (wg & 7) >> 2;   // 0..1  (b tile of 128)
  const int nt = wg & 3;          // 0..3  (k tile of 128)
  const int t = threadIdx.x;
  const int lane = t & 63;
  const int w = t >> 6;
  const int wm = w >> 1, wn = w & 1;

  const unsigned short* aH = Ehi + (size_t)(sd * MB + mt * 128) * NN;
  const unsigned short* aL = Elo + (size_t)(sd * MB + mt * 128) * NN;
  const unsigned short* bH = Bthi + (size_t)(sd * KK + nt * 128) * NN;
  const unsigned short* bL = Btlo + (size_t)(sd * KK + nt * 128) * NN;

  f32x4 acc4[4][4] = {};

  for (int kt = 0; kt < 8; ++kt) {
    __syncthreads();
    const int kb = kt * 64;
#pragma unroll
    for (int q = 0; q < 4; ++q) {
      int gg = q * 256 + t;
      int row = gg >> 3;
      int c8 = (gg & 7) * 8;
      size_t so = (size_t)row * NN + kb + c8;
      GLL16(aH + so, &sAhi[gg * 8]);
      GLL16(aL + so, &sAlo[gg * 8]);
      GLL16(bH + so, &sBhi[gg * 8]);
      GLL16(bL + so, &sBlo[gg * 8]);
    }
    __syncthreads();
#pragma unroll
    for (int kk = 0; kk < 64; kk += 32) {
      bf16x8 ah[4], al[4], bh[4], bl[4];
      const int fo = kk + (lane >> 4) * 8;
      const int fr = lane & 15;
#pragma unroll
      for (int m = 0; m < 4; ++m) {
        int off = (wm * 64 + m * 16 + fr) * 64 + fo;
        ah[m] = *(const bf16x8*)&sAhi[off];
        al[m] = *(const bf16x8*)&sAlo[off];
      }
#pragma unroll
      for (int n = 0; n < 4; ++n) {
        int off = (wn * 64 + n * 16 + fr) * 64 + fo;
        bh[n] = *(const bf16x8*)&sBhi[off];
        bl[n] = *(const bf16x8*)&sBlo[off];
      }
#pragma unroll
      for (int m = 0; m < 4; ++m)
#pragma unroll
        for (int n = 0; n < 4; ++n) {
          acc4[m][n] = __builtin_amdgcn_mfma_f32_16x16x32_bf16(ah[m], bh[n], acc4[m][n], 0, 0, 0);
          acc4[m][n] = __builtin_amdgcn_mfma_f32_16x16x32_bf16(ah[m], bl[n], acc4[m][n], 0, 0, 0);
          acc4[m][n] = __builtin_amdgcn_mfma_f32_16x16x32_bf16(al[m], bh[n], acc4[m][n], 0, 0, 0);
        }
    }
  }

  // epilogue: out = log(C) - logsum[k]
  const size_t obase = (size_t)sd * MB * KK;
  const int colb = nt * 128 + wn * 64;
  float ls[4];
#pragma unroll
  for (int n = 0; n < 4; ++n) ls[n] = logsum[sd * KK + colb + n * 16 + (lane & 15)];
#pragma unroll
  for (int m = 0; m < 4; ++m) {
    int rowb = mt * 128 + wm * 64 + m * 16 + (lane >> 4) * 4;
#pragma unroll
    for (int n = 0; n < 4; ++n) {
      int col = colb + n * 16 + (lane & 15);
      f32x4 v = acc4[m][n];
#pragma unroll
      for (int q = 0; q < 4; ++q)
        out[obase + (size_t)(rowb + q) * KK + col] = __logf(v[q]) - ls[n];
    }
  }
}

// ---------------- fallback (ws too small): fp32 LDS-tiled, no workspace ------
__global__ __launch_bounds__(256) void fb_gemm(const float* __restrict__ x,
                                               const float* __restrict__ wacc,
                                               float* __restrict__ out) {
  const int bx = blockIdx.x;
  const int sd = bx >> 5;
  const int bt = (bx & 31) >> 3;
  const int kt = bx & 7;
  const int b0 = bt * 64, k0 = kt * 64;
  __shared__ float sA[64 * 33];
  __shared__ float sB[32 * 65];
  __shared__ float sLs[64];
  const int t = threadIdx.x;
  float ca[4][4] = {{0.f}};
  const float* xp = x + (size_t)(sd * MB + b0) * NN;
  const float* ap = wacc + (size_t)sd * NN * KK + k0;

  for (int n0 = 0; n0 < NN; n0 += 32) {
    __syncthreads();
#pragma unroll
    for (int q = 0; q < 8; ++q) {
      int e = q * 256 + t;
      int r = e >> 5, c = e & 31;
      sA[r * 33 + c] = __expf(xp[(size_t)r * NN + n0 + c]);
    }
#pragma unroll
    for (int q = 0; q < 8; ++q) {
      int e = q * 256 + t;
      int r = e >> 6, c = e & 63;
      sB[r * 65 + c] = ap[(size_t)(n0 + r) * KK + c];
    }
    __syncthreads();
    const int tr = (t >> 4) * 4, tc = (t & 15) * 4;
    for (int n = 0; n < 32; ++n) {
      float bv0 = sB[n * 65 + tc], bv1 = sB[n * 65 + tc + 1];
      float bv2 = sB[n * 65 + tc + 2], bv3 = sB[n * 65 + tc + 3];
#pragma unroll
      for (int i = 0; i < 4; ++i) {
        float a = sA[(tr + i) * 33 + n];
        ca[i][0] += a * bv0; ca[i][1] += a * bv1;
        ca[i][2] += a * bv2; ca[i][3] += a * bv3;
      }
    }
  }
  __syncthreads();
  if (t < 64) {
    float s = 0.f;
    for (int n = 0; n < NN; ++n) s += ap[(size_t)n * KK + t];
    sLs[t] = __logf(s);
  }
  __syncthreads();
  const int tr = (t >> 4) * 4, tc = (t & 15) * 4;
#pragma unroll
  for (int i = 0; i < 4; ++i)
#pragma unroll
    for (int j2 = 0; j2 < 4; ++j2)
      out[(size_t)(sd * MB + b0 + tr + i) * KK + k0 + tc + j2] = __logf(ca[i][j2]) - sLs[tc + j2];
}

extern "C" void kernel_launch(void* const* d_in, const int* in_sizes, int n_in,
                              void* d_out, int out_size, void* d_ws, size_t ws_size,
                              hipStream_t stream) {
  const float* x = (const float*)d_in[0];
  const float* wacc = (const float*)d_in[1];
  float* out = (float*)d_out;

  const size_t E_ELEMS = (size_t)SD_TOT * MB * NN;   // 33,554,432
  const size_t B_ELEMS = (size_t)SD_TOT * KK * NN;   // 67,108,864
  const size_t NEED = 2 * E_ELEMS * 2 + 2 * B_ELEMS * 2 + (size_t)SD_TOT * KK * 4; // 403,177,472 B

  if (ws_size >= NEED) {
    unsigned short* Ehi = (unsigned short*)d_ws;
    unsigned short* Elo = Ehi + E_ELEMS;
    unsigned short* Bthi = (unsigned short*)((char*)d_ws + 2 * E_ELEMS * 2);
    unsigned short* Btlo = Bthi + B_ELEMS;
    float* logsum = (float*)((char*)d_ws + 2 * E_ELEMS * 2 + 2 * B_ELEMS * 2);

    prep_x<<<dim3(16384), dim3(256), 0, stream>>>(x, Ehi, Elo);
    prep_acc<<<dim3(2048), dim3(256), 0, stream>>>(wacc, Bthi, Btlo, logsum);
    gemm_split<<<dim3(2048), dim3(256), 0, stream>>>(Ehi, Elo, Bthi, Btlo, logsum, out);
  } else {
    fb_gemm<<<dim3(8192), dim3(256), 0, stream>>>(x, wacc, out);
  }
}

// Round 2
// 699.365 us; speedup vs baseline: 1.0678x; 1.0678x over previous
//
#include <hip/hip_runtime.h>
#include <hip/hip_bf16.h>

// out[s,d,b,k] = log( sum_n exp(x[s,d,b,n]) * acc[s,d,n,k] ) - log( sum_n acc[s,d,n,k] )
// S=32 D=8 B=256 N=512 K=512 ; SD = 256 independent 256x512x512 GEMMs.
// Split-bf16 (hi/lo) 3-MFMA GEMM, both operands K-major (acc transposed in prep).

typedef __attribute__((ext_vector_type(8))) __bf16 bf16x8;
typedef __attribute__((ext_vector_type(4))) float f32x4;
typedef __attribute__((ext_vector_type(8))) unsigned short u16x8;

#define SD_TOT 256
#define MB 256     // b per sd
#define NN 512     // n (contraction)
#define KK 512     // k (output cols)

__device__ inline unsigned short bf16rn(float f) {
  unsigned int u = __float_as_uint(f);
  u += 0x7fffu + ((u >> 16) & 1u);
  return (unsigned short)(u >> 16);
}
__device__ inline float bf16tof(unsigned short h) {
  return __uint_as_float(((unsigned int)h) << 16);
}

typedef __attribute__((address_space(1))) const unsigned char gas_byte;
typedef __attribute__((address_space(3))) unsigned char las_byte;
#define GLL16(gp, lp) __builtin_amdgcn_global_load_lds((gas_byte*)(const void*)(gp), (las_byte*)(void*)(lp), 16, 0, 0)

// ---------------- prep_x: E = exp(x), split to hi/lo bf16 planes -------------
// Fix vs r1: single 16B ushort8 store per plane (was 2x 8B at 16B stride = half-density).
__global__ __launch_bounds__(256) void prep_x(const float* __restrict__ x,
                                              unsigned short* __restrict__ Ehi,
                                              unsigned short* __restrict__ Elo) {
  size_t i = ((size_t)blockIdx.x * 256 + threadIdx.x) * 8;
  float4 v0 = *(const float4*)(x + i);
  float4 v1 = *(const float4*)(x + i + 4);
  float e[8] = {__expf(v0.x), __expf(v0.y), __expf(v0.z), __expf(v0.w),
                __expf(v1.x), __expf(v1.y), __expf(v1.z), __expf(v1.w)};
  u16x8 H, L;
#pragma unroll
  for (int j = 0; j < 8; ++j) {
    unsigned short h = bf16rn(e[j]);
    H[j] = h;
    L[j] = bf16rn(e[j] - bf16tof(h));
  }
  *(u16x8*)(Ehi + i) = H;
  *(u16x8*)(Elo + i) = L;
}

// -------- prep_acc: transpose acc[sd][n][k] -> Bt[sd][k][n] split hi/lo, plus
// logsum[sd][k] = log(sum_n acc). Block = (sd, 128-wide k tile); loops 8 n-chunks of 64.
// float4 reads, odd-pad LDS transpose (2-way bank = free), ushort4 dense writes.
__global__ __launch_bounds__(256) void prep_acc(const float* __restrict__ wacc,
                                                unsigned short* __restrict__ Bthi,
                                                unsigned short* __restrict__ Btlo,
                                                float* __restrict__ logsum) {
  __shared__ unsigned int tile[64 * 129];   // [n=64][k=128 +pad], hi|lo<<16 packed
  __shared__ float part[128 * 16];
  const int t = threadIdx.x;
  const int sd = blockIdx.x >> 2;
  const int k0 = (blockIdx.x & 3) << 7;
  const float* src = wacc + (size_t)sd * NN * KK + k0;
  float preg[8] = {0.f, 0.f, 0.f, 0.f, 0.f, 0.f, 0.f, 0.f};

  for (int ch = 0; ch < 8; ++ch) {
    const int n0 = ch * 64;
    __syncthreads();
#pragma unroll
    for (int ii = 0; ii < 8; ++ii) {
      int idx = ii * 256 + t;
      int r = idx >> 5;        // n row 0..63
      int c4 = idx & 31;       // float4 col
      float4 v = *(const float4*)(src + (size_t)(n0 + r) * KK + c4 * 4);
      float vv[4] = {v.x, v.y, v.z, v.w};
#pragma unroll
      for (int j = 0; j < 4; ++j) {
        unsigned int h = bf16rn(vv[j]);
        unsigned int l = bf16rn(vv[j] - bf16tof((unsigned short)h));
        tile[r * 129 + c4 * 4 + j] = h | (l << 16);
      }
    }
    __syncthreads();
#pragma unroll
    for (int ii = 0; ii < 8; ++ii) {
      int k = (t >> 4) + 16 * ii;     // 0..127
      int n4 = (t & 15) * 4;          // 0..60
      unsigned int w0 = tile[(n4 + 0) * 129 + k];
      unsigned int w1 = tile[(n4 + 1) * 129 + k];
      unsigned int w2 = tile[(n4 + 2) * 129 + k];
      unsigned int w3 = tile[(n4 + 3) * 129 + k];
      size_t ob = ((size_t)(sd * KK + k0 + k)) * NN + n0 + n4;
      *(ushort4*)(Bthi + ob) = make_ushort4((unsigned short)(w0 & 0xffffu), (unsigned short)(w1 & 0xffffu),
                                            (unsigned short)(w2 & 0xffffu), (unsigned short)(w3 & 0xffffu));
      *(ushort4*)(Btlo + ob) = make_ushort4((unsigned short)(w0 >> 16), (unsigned short)(w1 >> 16),
                                            (unsigned short)(w2 >> 16), (unsigned short)(w3 >> 16));
      preg[ii] += (bf16tof((unsigned short)(w0 & 0xffffu)) + bf16tof((unsigned short)(w0 >> 16))) +
                  (bf16tof((unsigned short)(w1 & 0xffffu)) + bf16tof((unsigned short)(w1 >> 16))) +
                  (bf16tof((unsigned short)(w2 & 0xffffu)) + bf16tof((unsigned short)(w2 >> 16))) +
                  (bf16tof((unsigned short)(w3 & 0xffffu)) + bf16tof((unsigned short)(w3 >> 16)));
    }
  }
  __syncthreads();
#pragma unroll
  for (int ii = 0; ii < 8; ++ii) {
    int k = (t >> 4) + 16 * ii;
    part[k * 16 + (t & 15)] = preg[ii];
  }
  __syncthreads();
  if (t < 128) {
    float s = 0.f;
#pragma unroll
    for (int g = 0; g < 16; ++g) s += part[t * 16 + g];
    logsum[sd * KK + k0 + t] = __logf(s);
  }
}

// ---------------- gemm: 256^2 tile, 8 waves, BK=64, 3-MFMA split, fused epilogue
__global__ __launch_bounds__(512, 2) void gemm_split(const unsigned short* __restrict__ Ehi,
                                                     const unsigned short* __restrict__ Elo,
                                                     const unsigned short* __restrict__ Bthi,
                                                     const unsigned short* __restrict__ Btlo,
                                                     const float* __restrict__ logsum,
                                                     float* __restrict__ out) {
  __shared__ __align__(16) unsigned short sAhi[256 * 64];
  __shared__ __align__(16) unsigned short sAlo[256 * 64];
  __shared__ __align__(16) unsigned short sBhi[256 * 64];
  __shared__ __align__(16) unsigned short sBlo[256 * 64];   // 128 KiB total

  const int bx = blockIdx.x;
  // 512 wg, XCD-chunked: consecutive logical wg (same sd's two nt blocks) share an XCD.
  const int wg = (bx & 7) * 64 + (bx >> 3);
  const int sd = wg >> 1;
  const int nt = wg & 1;
  const int t = threadIdx.x;     // 0..511
  const int lane = t & 63;
  const int w = t >> 6;          // 0..7
  const int wm = w >> 2;         // 0..1 : 128-row half
  const int wn = w & 3;          // 0..3 : 64-col quarter

  const unsigned short* aH = Ehi + (size_t)sd * MB * NN;
  const unsigned short* aL = Elo + (size_t)sd * MB * NN;
  const unsigned short* bH = Bthi + (size_t)(sd * KK + nt * 256) * NN;
  const unsigned short* bL = Btlo + (size_t)(sd * KK + nt * 256) * NN;

  f32x4 acc[8][4] = {};

  for (int kt = 0; kt < 8; ++kt) {
    __syncthreads();
    const int kb = kt * 64;
#pragma unroll
    for (int q = 0; q < 4; ++q) {
      int gg = q * 512 + t;
      int row = gg >> 3;          // 0..255
      int c8 = (gg & 7) * 8;      // 0..56
      size_t so = (size_t)row * NN + kb + c8;
      GLL16(aH + so, &sAhi[gg * 8]);
      GLL16(aL + so, &sAlo[gg * 8]);
      GLL16(bH + so, &sBhi[gg * 8]);
      GLL16(bL + so, &sBlo[gg * 8]);
    }
    __syncthreads();
#pragma unroll
    for (int kk = 0; kk < 64; kk += 32) {
      const int fo = kk + (lane >> 4) * 8;
      const int fr = lane & 15;
      bf16x8 bh[4], bl[4];
#pragma unroll
      for (int n = 0; n < 4; ++n) {
        int off = (wn * 64 + n * 16 + fr) * 64 + fo;
        bh[n] = *(const bf16x8*)&sBhi[off];
        bl[n] = *(const bf16x8*)&sBlo[off];
      }
#pragma unroll
      for (int m = 0; m < 8; ++m) {
        int offa = (wm * 128 + m * 16 + fr) * 64 + fo;
        bf16x8 ah = *(const bf16x8*)&sAhi[offa];
        bf16x8 al = *(const bf16x8*)&sAlo[offa];
#pragma unroll
        for (int n = 0; n < 4; ++n) {
          acc[m][n] = __builtin_amdgcn_mfma_f32_16x16x32_bf16(ah, bh[n], acc[m][n], 0, 0, 0);
          acc[m][n] = __builtin_amdgcn_mfma_f32_16x16x32_bf16(ah, bl[n], acc[m][n], 0, 0, 0);
          acc[m][n] = __builtin_amdgcn_mfma_f32_16x16x32_bf16(al, bh[n], acc[m][n], 0, 0, 0);
        }
      }
    }
  }

  // epilogue: out = log(C) - logsum[k]
  const size_t obase = (size_t)sd * MB * KK;
  const int colb = nt * 256 + wn * 64;
  float ls[4];
#pragma unroll
  for (int n = 0; n < 4; ++n) ls[n] = logsum[sd * KK + colb + n * 16 + (lane & 15)];
#pragma unroll
  for (int m = 0; m < 8; ++m) {
    int rowb = wm * 128 + m * 16 + (lane >> 4) * 4;
#pragma unroll
    for (int n = 0; n < 4; ++n) {
      int col = colb + n * 16 + (lane & 15);
      f32x4 v = acc[m][n];
#pragma unroll
      for (int q = 0; q < 4; ++q)
        out[obase + (size_t)(rowb + q) * KK + col] = __logf(v[q]) - ls[n];
    }
  }
}

// ---------------- fallback (ws too small): fp32 LDS-tiled, no workspace ------
__global__ __launch_bounds__(256) void fb_gemm(const float* __restrict__ x,
                                               const float* __restrict__ wacc,
                                               float* __restrict__ out) {
  const int bx = blockIdx.x;
  const int sd = bx >> 5;
  const int bt = (bx & 31) >> 3;
  const int kt = bx & 7;
  const int b0 = bt * 64, k0 = kt * 64;
  __shared__ float sA[64 * 33];
  __shared__ float sB[32 * 65];
  __shared__ float sLs[64];
  const int t = threadIdx.x;
  float ca[4][4] = {{0.f}};
  const float* xp = x + (size_t)(sd * MB + b0) * NN;
  const float* ap = wacc + (size_t)sd * NN * KK + k0;

  for (int n0 = 0; n0 < NN; n0 += 32) {
    __syncthreads();
#pragma unroll
    for (int q = 0; q < 8; ++q) {
      int e = q * 256 + t;
      int r = e >> 5, c = e & 31;
      sA[r * 33 + c] = __expf(xp[(size_t)r * NN + n0 + c]);
    }
#pragma unroll
    for (int q = 0; q < 8; ++q) {
      int e = q * 256 + t;
      int r = e >> 6, c = e & 63;
      sB[r * 65 + c] = ap[(size_t)(n0 + r) * KK + c];
    }
    __syncthreads();
    const int tr = (t >> 4) * 4, tc = (t & 15) * 4;
    for (int n = 0; n < 32; ++n) {
      float bv0 = sB[n * 65 + tc], bv1 = sB[n * 65 + tc + 1];
      float bv2 = sB[n * 65 + tc + 2], bv3 = sB[n * 65 + tc + 3];
#pragma unroll
      for (int i = 0; i < 4; ++i) {
        float a = sA[(tr + i) * 33 + n];
        ca[i][0] += a * bv0; ca[i][1] += a * bv1;
        ca[i][2] += a * bv2; ca[i][3] += a * bv3;
      }
    }
  }
  __syncthreads();
  if (t < 64) {
    float s = 0.f;
    for (int n = 0; n < NN; ++n) s += ap[(size_t)n * KK + t];
    sLs[t] = __logf(s);
  }
  __syncthreads();
  const int tr = (t >> 4) * 4, tc = (t & 15) * 4;
#pragma unroll
  for (int i = 0; i < 4; ++i)
#pragma unroll
    for (int j2 = 0; j2 < 4; ++j2)
      out[(size_t)(sd * MB + b0 + tr + i) * KK + k0 + tc + j2] = __logf(ca[i][j2]) - sLs[tc + j2];
}

extern "C" void kernel_launch(void* const* d_in, const int* in_sizes, int n_in,
                              void* d_out, int out_size, void* d_ws, size_t ws_size,
                              hipStream_t stream) {
  const float* x = (const float*)d_in[0];
  const float* wacc = (const float*)d_in[1];
  float* out = (float*)d_out;

  const size_t E_ELEMS = (size_t)SD_TOT * MB * NN;   // 33,554,432
  const size_t B_ELEMS = (size_t)SD_TOT * KK * NN;   // 67,108,864
  const size_t NEED = 2 * E_ELEMS * 2 + 2 * B_ELEMS * 2 + (size_t)SD_TOT * KK * 4;

  if (ws_size >= NEED) {
    unsigned short* Ehi = (unsigned short*)d_ws;
    unsigned short* Elo = Ehi + E_ELEMS;
    unsigned short* Bthi = (unsigned short*)((char*)d_ws + 2 * E_ELEMS * 2);
    unsigned short* Btlo = Bthi + B_ELEMS;
    float* logsum = (float*)((char*)d_ws + 2 * E_ELEMS * 2 + 2 * B_ELEMS * 2);

    prep_x<<<dim3(16384), dim3(256), 0, stream>>>(x, Ehi, Elo);
    prep_acc<<<dim3(1024), dim3(256), 0, stream>>>(wacc, Bthi, Btlo, logsum);
    gemm_split<<<dim3(512), dim3(512), 0, stream>>>(Ehi, Elo, Bthi, Btlo, logsum, out);
  } else {
    fb_gemm<<<dim3(8192), dim3(256), 0, stream>>>(x, wacc, out);
  }
}

// Round 4
// 630.017 us; speedup vs baseline: 1.1853x; 1.1101x over previous
//
#include <hip/hip_runtime.h>
#include <hip/hip_bf16.h>

// out[s,d,b,k] = log( sum_n exp(x[s,d,b,n]) * acc[s,d,n,k] ) - log( sum_n acc[s,d,n,k] )
// S=32 D=8 B=256 N=512 K=512 ; SD = 256 independent 256x512x512 GEMMs.
// Round 3 (re-run): prep_x fused into gemm; XOR-swizzled LDS (conflict-free frag
// reads); prep_acc at 8x occupancy. Split-bf16 (hi/lo) 3-MFMA precision scheme kept.

typedef __attribute__((ext_vector_type(8))) __bf16 bf16x8;
typedef __attribute__((ext_vector_type(4))) float f32x4;
typedef __attribute__((ext_vector_type(8))) unsigned short u16x8;

#define SD_TOT 256
#define MB 256     // b per sd
#define NN 512     // n (contraction)
#define KK 512     // k (output cols)
#define B_ELEMS ((size_t)SD_TOT * KK * NN)   // per bf16 plane of Bt

__device__ inline unsigned short bf16rn(float f) {
  unsigned int u = __float_as_uint(f);
  u += 0x7fffu + ((u >> 16) & 1u);
  return (unsigned short)(u >> 16);
}
__device__ inline float bf16tof(unsigned short h) {
  return __uint_as_float(((unsigned int)h) << 16);
}

typedef __attribute__((address_space(1))) const unsigned char gas_byte;
typedef __attribute__((address_space(3))) unsigned char las_byte;
#define GLL16(gp, lp) __builtin_amdgcn_global_load_lds((gas_byte*)(const void*)(gp), (las_byte*)(void*)(lp), 16, 0, 0)

// -------- prep_acc: transpose acc[sd][n][k] -> Bt[sd][k][n] split hi/lo, plus
// logsum[sd][k] = log(sum_n acc). Block = (sd, 64-wide k tile): grid 2048,
// ~21 KB LDS -> ~7 blocks/CU (was 44% occupancy at 41 KB / 1024 blocks).
__global__ __launch_bounds__(256) void prep_acc(const float* __restrict__ wacc,
                                                unsigned short* __restrict__ Bthi,
                                                unsigned short* __restrict__ Btlo,
                                                float* __restrict__ logsum) {
  __shared__ unsigned int tile[64 * 65];   // [n=64][k=64 +pad], hi|lo<<16 packed
  __shared__ float part[64 * 16];
  const int t = threadIdx.x;
  const int sd = blockIdx.x >> 3;
  const int k0 = (blockIdx.x & 7) << 6;
  const float* src = wacc + (size_t)sd * NN * KK + k0;
  float preg[4] = {0.f, 0.f, 0.f, 0.f};

  for (int ch = 0; ch < 8; ++ch) {
    const int n0 = ch * 64;
    __syncthreads();
#pragma unroll
    for (int ii = 0; ii < 4; ++ii) {
      int idx = ii * 256 + t;
      int r = idx >> 4;        // n row 0..63
      int c4 = idx & 15;       // float4 col 0..15
      float4 v = *(const float4*)(src + (size_t)(n0 + r) * KK + c4 * 4);
      float vv[4] = {v.x, v.y, v.z, v.w};
#pragma unroll
      for (int j = 0; j < 4; ++j) {
        unsigned int h = bf16rn(vv[j]);
        unsigned int l = bf16rn(vv[j] - bf16tof((unsigned short)h));
        tile[r * 65 + c4 * 4 + j] = h | (l << 16);
      }
    }
    __syncthreads();
#pragma unroll
    for (int ii = 0; ii < 4; ++ii) {
      int k = (t >> 4) + 16 * ii;     // 0..63
      int n4 = (t & 15) * 4;          // 0..60
      unsigned int w0 = tile[(n4 + 0) * 65 + k];
      unsigned int w1 = tile[(n4 + 1) * 65 + k];
      unsigned int w2 = tile[(n4 + 2) * 65 + k];
      unsigned int w3 = tile[(n4 + 3) * 65 + k];
      size_t ob = ((size_t)(sd * KK + k0 + k)) * NN + n0 + n4;
      *(ushort4*)(Bthi + ob) = make_ushort4((unsigned short)(w0 & 0xffffu), (unsigned short)(w1 & 0xffffu),
                                            (unsigned short)(w2 & 0xffffu), (unsigned short)(w3 & 0xffffu));
      *(ushort4*)(Btlo + ob) = make_ushort4((unsigned short)(w0 >> 16), (unsigned short)(w1 >> 16),
                                            (unsigned short)(w2 >> 16), (unsigned short)(w3 >> 16));
      preg[ii] += (bf16tof((unsigned short)(w0 & 0xffffu)) + bf16tof((unsigned short)(w0 >> 16))) +
                  (bf16tof((unsigned short)(w1 & 0xffffu)) + bf16tof((unsigned short)(w1 >> 16))) +
                  (bf16tof((unsigned short)(w2 & 0xffffu)) + bf16tof((unsigned short)(w2 >> 16))) +
                  (bf16tof((unsigned short)(w3 & 0xffffu)) + bf16tof((unsigned short)(w3 >> 16)));
    }
  }
  __syncthreads();
#pragma unroll
  for (int ii = 0; ii < 4; ++ii) {
    int k = (t >> 4) + 16 * ii;
    part[k * 16 + (t & 15)] = preg[ii];
  }
  __syncthreads();
  if (t < 64) {
    float s = 0.f;
#pragma unroll
    for (int g = 0; g < 16; ++g) s += part[t * 16 + g];
    logsum[sd * KK + k0 + t] = __logf(s);
  }
}

// ---------------- gemm: 256x256 tile (k-split), 8 waves, BK=64, fused exp(x) A
// LDS rows: 256 B = [plane(2)][n(64)] bf16 = 16 granules of 16 B, XOR-swizzled
// G = L ^ (row&15)  -> fragment reads conflict-free. A reg-staged (exp+split),
// B via global_load_lds with PRE-SWIZZLED global source (linear LDS dest).
__global__ __launch_bounds__(512) void gemm_fused(const float* __restrict__ x,
                                                  const unsigned short* __restrict__ Bthi,
                                                  const float* __restrict__ logsum,
                                                  float* __restrict__ out) {
  __shared__ __align__(16) unsigned char sA[65536];   // [row 256][256 B swizzled]
  __shared__ __align__(16) unsigned char sB[65536];   // [kcol 256][256 B swizzled]

  const int bx = blockIdx.x;
  const int wg = (bx & 7) * 64 + (bx >> 3);  // XCD-chunked; sd's two halves colocate
  const int sd = wg >> 1;
  const int nt = wg & 1;
  const int t = threadIdx.x;     // 0..511
  const int lane = t & 63;
  const int fr = lane & 15;
  const int fq = lane >> 4;      // 0..3
  const int w = t >> 6;          // 0..7
  const int wm = w >> 2;         // 0..1 : 128-row half
  const int wn = w & 3;          // 0..3 : 64-col quarter

  const float* xp = x + (size_t)sd * MB * NN;
  const int base_col = sd * KK + nt * 256;

  f32x4 acc[8][4] = {};

  const int arow = t >> 1;
  const int nl0 = (t & 1) * 32;

  for (int kt = 0; kt < 8; ++kt) {
    const int n0 = kt * 64;
    __syncthreads();
    // ---- A stage: read x fp32, exp, split hi/lo, swizzled ds_write_b128 ----
    const float* ap = xp + (size_t)arow * NN + n0 + nl0;
    float e[32];
#pragma unroll
    for (int q = 0; q < 8; ++q) {
      float4 v = *(const float4*)(ap + q * 4);
      e[q * 4 + 0] = __expf(v.x); e[q * 4 + 1] = __expf(v.y);
      e[q * 4 + 2] = __expf(v.z); e[q * 4 + 3] = __expf(v.w);
    }
    unsigned short hi[32], lo[32];
#pragma unroll
    for (int j = 0; j < 32; ++j) {
      hi[j] = bf16rn(e[j]);
      lo[j] = bf16rn(e[j] - bf16tof(hi[j]));
    }
#pragma unroll
    for (int q = 0; q < 4; ++q) {
      int L = (nl0 >> 3) + q;            // hi plane granule 0..7
      int G = L ^ (arow & 15);
      u16x8 v;
#pragma unroll
      for (int j = 0; j < 8; ++j) v[j] = hi[q * 8 + j];
      *(u16x8*)(sA + arow * 256 + G * 16) = v;
      int L2 = 8 + (nl0 >> 3) + q;       // lo plane
      int G2 = L2 ^ (arow & 15);
      u16x8 v2;
#pragma unroll
      for (int j = 0; j < 8; ++j) v2[j] = lo[q * 8 + j];
      *(u16x8*)(sA + arow * 256 + G2 * 16) = v2;
    }
    // ---- B stage: linear LDS dest, pre-swizzled global source ----
#pragma unroll
    for (int q = 0; q < 8; ++q) {
      int S = q * 512 + t;               // linear 16B slot, = lane-linear per wave
      int kcol = S >> 4;
      int G = S & 15;
      int L = G ^ (kcol & 15);
      int p = L >> 3;                    // 0 = hi plane, 1 = lo plane
      int nl = (L & 7) * 8;
      const unsigned short* srcp = Bthi + (size_t)p * B_ELEMS +
                                   (size_t)(base_col + kcol) * NN + n0 + nl;
      GLL16(srcp, sB + (size_t)S * 16);
    }
    __syncthreads();
    // ---- compute ----
#pragma unroll
    for (int kk = 0; kk < 2; ++kk) {
      bf16x8 bh[4], bl[4];
#pragma unroll
      for (int n = 0; n < 4; ++n) {
        int C = wn * 64 + n * 16 + fr;
        int Lh = kk * 4 + fq;
        bh[n] = *(const bf16x8*)(sB + C * 256 + ((Lh) ^ (C & 15)) * 16);
        bl[n] = *(const bf16x8*)(sB + C * 256 + ((Lh + 8) ^ (C & 15)) * 16);
      }
#pragma unroll
      for (int m = 0; m < 8; ++m) {
        int R = wm * 128 + m * 16 + fr;
        int Lh = kk * 4 + fq;
        bf16x8 ah = *(const bf16x8*)(sA + R * 256 + ((Lh) ^ (R & 15)) * 16);
        bf16x8 al = *(const bf16x8*)(sA + R * 256 + ((Lh + 8) ^ (R & 15)) * 16);
#pragma unroll
        for (int n = 0; n < 4; ++n) {
          acc[m][n] = __builtin_amdgcn_mfma_f32_16x16x32_bf16(ah, bh[n], acc[m][n], 0, 0, 0);
          acc[m][n] = __builtin_amdgcn_mfma_f32_16x16x32_bf16(ah, bl[n], acc[m][n], 0, 0, 0);
          acc[m][n] = __builtin_amdgcn_mfma_f32_16x16x32_bf16(al, bh[n], acc[m][n], 0, 0, 0);
        }
      }
    }
  }

  // epilogue: out = log(C) - logsum[k]
  const size_t obase = (size_t)sd * MB * KK;
  const int colb = nt * 256 + wn * 64;
  float ls[4];
#pragma unroll
  for (int n = 0; n < 4; ++n) ls[n] = logsum[sd * KK + colb + n * 16 + fr];
#pragma unroll
  for (int m = 0; m < 8; ++m) {
    int rowb = wm * 128 + m * 16 + fq * 4;
#pragma unroll
    for (int n = 0; n < 4; ++n) {
      int col = colb + n * 16 + fr;
      f32x4 v = acc[m][n];
#pragma unroll
      for (int q = 0; q < 4; ++q)
        out[obase + (size_t)(rowb + q) * KK + col] = __logf(v[q]) - ls[n];
    }
  }
}

// ---------------- fallback (ws too small): fp32 LDS-tiled, no workspace ------
__global__ __launch_bounds__(256) void fb_gemm(const float* __restrict__ x,
                                               const float* __restrict__ wacc,
                                               float* __restrict__ out) {
  const int bx = blockIdx.x;
  const int sd = bx >> 5;
  const int bt = (bx & 31) >> 3;
  const int kt = bx & 7;
  const int b0 = bt * 64, k0 = kt * 64;
  __shared__ float sA[64 * 33];
  __shared__ float sB[32 * 65];
  __shared__ float sLs[64];
  const int t = threadIdx.x;
  float ca[4][4] = {{0.f}};
  const float* xp = x + (size_t)(sd * MB + b0) * NN;
  const float* ap = wacc + (size_t)sd * NN * KK + k0;

  for (int n0 = 0; n0 < NN; n0 += 32) {
    __syncthreads();
#pragma unroll
    for (int q = 0; q < 8; ++q) {
      int e = q * 256 + t;
      int r = e >> 5, c = e & 31;
      sA[r * 33 + c] = __expf(xp[(size_t)r * NN + n0 + c]);
    }
#pragma unroll
    for (int q = 0; q < 8; ++q) {
      int e = q * 256 + t;
      int r = e >> 6, c = e & 63;
      sB[r * 65 + c] = ap[(size_t)(n0 + r) * KK + c];
    }
    __syncthreads();
    const int tr = (t >> 4) * 4, tc = (t & 15) * 4;
    for (int n = 0; n < 32; ++n) {
      float bv0 = sB[n * 65 + tc], bv1 = sB[n * 65 + tc + 1];
      float bv2 = sB[n * 65 + tc + 2], bv3 = sB[n * 65 + tc + 3];
#pragma unroll
      for (int i = 0; i < 4; ++i) {
        float a = sA[(tr + i) * 33 + n];
        ca[i][0] += a * bv0; ca[i][1] += a * bv1;
        ca[i][2] += a * bv2; ca[i][3] += a * bv3;
      }
    }
  }
  __syncthreads();
  if (t < 64) {
    float s = 0.f;
    for (int n = 0; n < NN; ++n) s += ap[(size_t)n * KK + t];
    sLs[t] = __logf(s);
  }
  __syncthreads();
  const int tr = (t >> 4) * 4, tc = (t & 15) * 4;
#pragma unroll
  for (int i = 0; i < 4; ++i)
#pragma unroll
    for (int j2 = 0; j2 < 4; ++j2)
      out[(size_t)(sd * MB + b0 + tr + i) * KK + k0 + tc + j2] = __logf(ca[i][j2]) - sLs[tc + j2];
}

extern "C" void kernel_launch(void* const* d_in, const int* in_sizes, int n_in,
                              void* d_out, int out_size, void* d_ws, size_t ws_size,
                              hipStream_t stream) {
  const float* x = (const float*)d_in[0];
  const float* wacc = (const float*)d_in[1];
  float* out = (float*)d_out;

  const size_t NEED = 2 * B_ELEMS * 2 + (size_t)SD_TOT * KK * 4;   // Bt hi/lo + logsum

  if (ws_size >= NEED) {
    unsigned short* Bthi = (unsigned short*)d_ws;
    unsigned short* Btlo = Bthi + B_ELEMS;
    float* logsum = (float*)((char*)d_ws + 2 * B_ELEMS * 2);

    prep_acc<<<dim3(2048), dim3(256), 0, stream>>>(wacc, Bthi, Btlo, logsum);
    gemm_fused<<<dim3(512), dim3(512), 0, stream>>>(x, Bthi, logsum, out);
  } else {
    fb_gemm<<<dim3(8192), dim3(256), 0, stream>>>(x, wacc, out);
  }
}